// Round 7
// baseline (93.717 us; speedup 1.0000x reference)
//
#include <hip/hip_runtime.h>
#include <hip/hip_bf16.h>
#include <stdint.h>

#define HH   96
#define WW   96
#define HW   9216
#define CIN  256
#define COUT 256
#define NB   2      // batch
#define NG   4      // groups
#define CG   64     // channels per group
#define KK   9
#define KTOT 2304   // CIN*KK
#define KB   288    // KTOT/8
#define TS   8      // sampler pixel tile side
#define WIN  12     // staged window side (TS + 4)
#define SCH  32     // sampler channels per block (one 8-ch pass per wave)

typedef __attribute__((ext_vector_type(8))) short short8;
typedef __attribute__((ext_vector_type(4))) float f32x4;
typedef __attribute__((ext_vector_type(4))) uint32_t u32x4;

__device__ __forceinline__ uint32_t pk2bf(float v0, float v1) {
    __hip_bfloat162 h = __float22bfloat162_rn(make_float2(v0, v1));  // v_cvt_pk_bf16_f32
    uint32_t u;
    __builtin_memcpy(&u, &h, 4);
    return u;
}

// ---------------------------------------------------------------------------
// Kernel 1: w_deform (COUT x CIN x 9 fp32) -> bf16, flat blocked [kb][o][8]
// K-order is kk-major: k' = kk*256 + c  (must match sampler's S layout)
// ---------------------------------------------------------------------------
__global__ __launch_bounds__(256) void prep_A(const float* __restrict__ wd,
                                              uint16_t* __restrict__ Ablk) {
    int t  = blockIdx.x * 256 + threadIdx.x;   // 73728 = 256*288
    int kb = t % KB;
    int o  = t / KB;
    int kkA = kb >> 5;            // (kb*8)/256
    int c0A = (kb & 31) * 8;      // (kb*8)%256
    const float* src = wd + (size_t)o * KTOT + c0A * KK + kkA;
    float a[8];
#pragma unroll
    for (int e = 0; e < 8; ++e) a[e] = src[e * KK];
    uint16_t* dst = Ablk + ((size_t)kb * 256 + o) * 8;
    u32x4 v;
    v.x = pk2bf(a[0], a[1]);
    v.y = pk2bf(a[2], a[3]);
    v.z = pk2bf(a[4], a[5]);
    v.w = pk2bf(a[6], a[7]);
    *(u32x4*)dst = v;
}

// ---------------------------------------------------------------------------
// Kernel 2: offsets + bilinear sampling -> S[b][kb][p][8] bf16 (kk-major K)
// block = 8x8 pixel tile x 32 channels, 256 thr; wave wv owns 8 channels ->
// ONE ch8 pass per kk. Window 32x12x12 fp32 = 18.4 KB LDS -> 8 blocks/CU
// (cap 32 waves/CU). woff reads are wave-uniform (s_load). In-loop
// clamp-aware separable weights (== reference's valid-masked bilinear).
// Global fallback for offsets escaping the +-2 guard band (never taken here).
// ---------------------------------------------------------------------------
__global__ __launch_bounds__(256) void sampler(const float* __restrict__ feature,
                                               const float* __restrict__ pred,
                                               const float* __restrict__ woff,
                                               uint16_t* __restrict__ S) {
    __shared__ float ft[SCH * WIN * WIN];  // 18432 B

    int tid = threadIdx.x;
    int cb = blockIdx.y, b = blockIdx.z;
    int ch0 = cb * SCH;                    // global channel base
    int g = ch0 >> 6;                      // group
    int ty = blockIdx.x / (WW / TS), tx = blockIdx.x % (WW / TS);
    int r0 = ty * TS, c0 = tx * TS;
    int rlo = min(max(r0 - 2, 0), HH - WIN);
    int clo = min(max(c0 - 2, 0), WW - WIN);

    // ---- stage feature window [ch][r][q] (fp32), 4608 elems / 256 thr
    const float* fg = feature + ((size_t)(b * CIN + ch0)) * HW;
    for (int e = tid; e < SCH * WIN * WIN; e += 256) {
        int ch = e / (WIN * WIN);
        int re = e - ch * (WIN * WIN);
        int rr = re / WIN, cc = re - rr * WIN;
        ft[e] = fg[(size_t)ch * HW + (rlo + rr) * WW + clo + cc];
    }
    __syncthreads();

    int lane = tid & 63, wv = tid >> 6;    // wv in {0..3}: channels wv*8..+8
    int lr = lane >> 3, lc = lane & 7;
    int hy = r0 + lr, hx = c0 + lc;
    int p = hy * WW + hx;
    float4 ps4 = *(const float4*)(pred + ((size_t)b * HW + p) * 4);

    const float* ftw = ft + (wv * 8) * (WIN * WIN);
    const float* fgw = fg + (size_t)(wv * 8) * HW;      // fallback base
    int kb_base = cb * 4 + wv;             // (ch0 + wv*8)/8

#pragma unroll
    for (int kk = 0; kk < KK; ++kk) {
        const float* wy = woff + (g * KK + kk) * 8;     // uniform -> s_load
        float offy = ps4.x * wy[0] + ps4.y * wy[1] + ps4.z * wy[2] + ps4.w * wy[3];
        float offx = ps4.x * wy[4] + ps4.y * wy[5] + ps4.z * wy[6] + ps4.w * wy[7];
        float py = (float)(hy - 1 + kk / 3) + offy;
        float px = (float)(hx - 1 + kk % 3) + offx;
        float fy = floorf(py), fx = floorf(px);
        int y0 = (int)fy, x0 = (int)fx;
        float ly = py - fy, lx = px - fx;
        int r = min(max(y0, 0), HH - 2);
        int q = min(max(x0, 0), WW - 2);
        float wyA = (y0 == r) ? (1.f - ly) : ((y0 == -1) ? ly : 0.f);
        float wyB = (y0 == r) ? ly : ((y0 == HH - 1) ? (1.f - ly) : 0.f);
        float wxA = (x0 == q) ? (1.f - lx) : ((x0 == -1) ? lx : 0.f);
        float wxB = (x0 == q) ? lx : ((x0 == WW - 1) ? (1.f - lx) : 0.f);
        float c00 = wyA * wxA, c01 = wyA * wxB;
        float c10 = wyB * wxA, c11 = wyB * wxB;

        bool fast = (r >= rlo) & (r <= rlo + WIN - 2) &
                    (q >= clo) & (q <= clo + WIN - 2);

        uint16_t* Sp = S + (((size_t)b * KB + (kk * 32 + kb_base)) * HW + p) * 8;
        uint32_t pk[4];

        if (fast) {
            int base = (r - rlo) * WIN + (q - clo);
#pragma unroll
            for (int ep = 0; ep < 4; ++ep) {
                const float* f0 = ftw + (2 * ep) * (WIN * WIN) + base;
                const float* f1 = f0 + (WIN * WIN);
                float v0 = c00 * f0[0] + c01 * f0[1] + c10 * f0[WIN] + c11 * f0[WIN + 1];
                float v1 = c00 * f1[0] + c01 * f1[1] + c10 * f1[WIN] + c11 * f1[WIN + 1];
                pk[ep] = pk2bf(v0, v1);
            }
        } else {
            size_t gb = (size_t)r * WW + q;
#pragma unroll
            for (int ep = 0; ep < 4; ++ep) {
                const float* f0 = fgw + (size_t)(2 * ep) * HW + gb;
                const float* f1 = f0 + HW;
                float v0 = c00 * f0[0] + c01 * f0[1] + c10 * f0[WW] + c11 * f0[WW + 1];
                float v1 = c00 * f1[0] + c01 * f1[1] + c10 * f1[WW] + c11 * f1[WW + 1];
                pk[ep] = pk2bf(v0, v1);
            }
        }
        u32x4 vv = {pk[0], pk[1], pk[2], pk[3]};
        *(u32x4*)(Sp) = vv;
    }
}

// ---------------------------------------------------------------------------
// Kernel 3: out[b,o,p] = relu( sum_k A[o,k] * S[k,p] )  (bf16 MFMA 16x16x32)
// 64x64 tile, K-step 64 -> grid 1152 (4.5 blocks/CU resident), 36 K-steps
// (half the barrier crossings). 4 waves, each 32x32 (2x2 frags, 8 MFMA/step).
// Depth-2 double-buffer (32 KB LDS), counted vmcnt(4) keeps next step's
// loads in flight across barriers.
// ---------------------------------------------------------------------------
__global__ __launch_bounds__(256) void gemm_kernel(const uint16_t* __restrict__ S,
                                                   const uint16_t* __restrict__ Ablk,
                                                   float* __restrict__ out) {
    __shared__ uint16_t sA[2][8 * 64 * 8];   // [buf][kb-chunk][row][8] 8 KB/buf
    __shared__ uint16_t sB[2][8 * 64 * 8];

    int tid = threadIdx.x;
    int lane = tid & 63, wv = tid >> 6;
    int wr = wv >> 1, wc = wv & 1;
    int col0 = blockIdx.x * 64;            // p tile (144)
    int o0   = blockIdx.y * 64;            // o tile (4)
    int b    = blockIdx.z;

    const uint16_t* Bg = S + (size_t)b * KB * HW * 8;

    f32x4 acc[2][2];
#pragma unroll
    for (int m = 0; m < 2; ++m)
#pragma unroll
        for (int n = 0; n < 2; ++n) acc[m][n] = (f32x4){0.f, 0.f, 0.f, 0.f};

    int kc = lane >> 4, il = lane & 15;
    const int NT = KTOT / 64;              // 36

    // wave wv stages kb-chunks {t*8+wv*2, t*8+wv*2+1}: 2 A + 2 B loads
    auto STAGE = [&](int t, int buf) {
#pragma unroll
        for (int j = 0; j < 2; ++j) {
            int kb = t * 8 + wv * 2 + j;
            int lc_ = wv * 2 + j;
            __builtin_amdgcn_global_load_lds(
                (const __attribute__((address_space(1))) uint32_t*)
                    (Ablk + ((size_t)kb * 256 + o0 + lane) * 8),
                (__attribute__((address_space(3))) uint32_t*)
                    (&sA[buf][(lc_ * 64 + lane) * 8]),
                16, 0, 0);
            __builtin_amdgcn_global_load_lds(
                (const __attribute__((address_space(1))) uint32_t*)
                    (Bg + ((size_t)kb * HW + col0 + lane) * 8),
                (__attribute__((address_space(3))) uint32_t*)
                    (&sB[buf][(lc_ * 64 + lane) * 8]),
                16, 0, 0);
        }
    };

    STAGE(0, 0);
    STAGE(1, 1);

    for (int t = 0; t < NT; ++t) {
        int cur = t & 1;
        if (t < NT - 1) {
            asm volatile("s_waitcnt vmcnt(4)\n\ts_barrier" ::: "memory");
        } else {
            asm volatile("s_waitcnt vmcnt(0)\n\ts_barrier" ::: "memory");
        }
        __builtin_amdgcn_sched_barrier(0);

        short8 af[2][2], bf[2][2];
#pragma unroll
        for (int h = 0; h < 2; ++h) {
#pragma unroll
            for (int m = 0; m < 2; ++m)
                af[h][m] = *(const short8*)(&sA[cur][((h * 4 + kc) * 64 + wr * 32 + m * 16 + il) * 8]);
#pragma unroll
            for (int n = 0; n < 2; ++n)
                bf[h][n] = *(const short8*)(&sB[cur][((h * 4 + kc) * 64 + wc * 32 + n * 16 + il) * 8]);
        }

#pragma unroll
        for (int h = 0; h < 2; ++h)
#pragma unroll
            for (int m = 0; m < 2; ++m)
#pragma unroll
                for (int n = 0; n < 2; ++n)
                    acc[m][n] = __builtin_amdgcn_mfma_f32_16x16x32_bf16(af[h][m], bf[h][n], acc[m][n], 0, 0, 0);

        // all waves done reading buf[cur], then refill it for step t+2
        asm volatile("s_waitcnt lgkmcnt(0)\n\ts_barrier" ::: "memory");
        __builtin_amdgcn_sched_barrier(0);
        if (t + 2 < NT) STAGE(t + 2, cur);
    }

    int r4 = (lane >> 4) * 4;
    size_t obase = ((size_t)b * COUT + o0 + wr * 32) * HW + col0 + wc * 32;
#pragma unroll
    for (int m = 0; m < 2; ++m)
#pragma unroll
        for (int n = 0; n < 2; ++n)
#pragma unroll
            for (int r = 0; r < 4; ++r) {
                float v = acc[m][n][r];
                v = v > 0.f ? v : 0.f;
                out[obase + (size_t)(m * 16 + r4 + r) * HW + n * 16 + il] = v;
            }
}

// ---------------------------------------------------------------------------
extern "C" void kernel_launch(void* const* d_in, const int* in_sizes, int n_in,
                              void* d_out, int out_size, void* d_ws, size_t ws_size,
                              hipStream_t stream) {
    (void)in_sizes; (void)n_in; (void)out_size; (void)ws_size;
    const float* feature = (const float*)d_in[0];
    const float* pred    = (const float*)d_in[1];
    const float* woff    = (const float*)d_in[2];
    const float* wdef    = (const float*)d_in[3];
    float* out = (float*)d_out;

    const size_t S_BYTES = (size_t)NB * KB * HW * 8 * 2;   // 84,934,656
    uint16_t* S    = (uint16_t*)d_ws;
    uint16_t* Ablk = (uint16_t*)((char*)d_ws + S_BYTES);

    hipLaunchKernelGGL(prep_A, dim3(288), dim3(256), 0, stream, wdef, Ablk);
    hipLaunchKernelGGL(sampler, dim3((HH / TS) * (WW / TS), CIN / SCH, NB), dim3(256), 0, stream,
                       feature, pred, woff, S);
    hipLaunchKernelGGL(gemm_kernel, dim3(HW / 64, COUT / 64, NB), dim3(256), 0, stream,
                       S, Ablk, out);
}

// Round 8
// 86.916 us; speedup vs baseline: 1.0782x; 1.0782x over previous
//
#include <hip/hip_runtime.h>
#include <hip/hip_bf16.h>
#include <stdint.h>

#define HH   96
#define WW   96
#define HW   9216
#define CIN  256
#define COUT 256
#define NB   2      // batch
#define NG   4      // groups
#define CG   64     // channels per group
#define KK   9
#define KTOT 2304   // CIN*KK
#define KB   288    // KTOT/8
#define TS   8      // sampler pixel tile side
#define WIN  12     // staged window side (TS + 4)
#define SCH  32     // sampler channels per block (one 8-ch pass per wave)

typedef __attribute__((ext_vector_type(8))) short short8;
typedef __attribute__((ext_vector_type(4))) float f32x4;
typedef __attribute__((ext_vector_type(4))) uint32_t u32x4;

__device__ __forceinline__ uint32_t pk2bf(float v0, float v1) {
    __hip_bfloat162 h = __float22bfloat162_rn(make_float2(v0, v1));  // v_cvt_pk_bf16_f32
    uint32_t u;
    __builtin_memcpy(&u, &h, 4);
    return u;
}

// ---------------------------------------------------------------------------
// Kernel 1: w_deform (COUT x CIN x 9 fp32) -> bf16, flat blocked [kb][o][8]
// K-order is kk-major: k' = kk*256 + c  (must match sampler's S layout)
// ---------------------------------------------------------------------------
__global__ __launch_bounds__(256) void prep_A(const float* __restrict__ wd,
                                              uint16_t* __restrict__ Ablk) {
    int t  = blockIdx.x * 256 + threadIdx.x;   // 73728 = 256*288
    int kb = t % KB;
    int o  = t / KB;
    int kkA = kb >> 5;            // (kb*8)/256
    int c0A = (kb & 31) * 8;      // (kb*8)%256
    const float* src = wd + (size_t)o * KTOT + c0A * KK + kkA;
    float a[8];
#pragma unroll
    for (int e = 0; e < 8; ++e) a[e] = src[e * KK];
    uint16_t* dst = Ablk + ((size_t)kb * 256 + o) * 8;
    u32x4 v;
    v.x = pk2bf(a[0], a[1]);
    v.y = pk2bf(a[2], a[3]);
    v.z = pk2bf(a[4], a[5]);
    v.w = pk2bf(a[6], a[7]);
    *(u32x4*)dst = v;
}

// ---------------------------------------------------------------------------
// Kernel 2: offsets + bilinear sampling -> S[b][kb][p][8] bf16 (kk-major K)
// block = 8x8 pixel tile x 32 channels, 256 thr; wave wv owns 8 channels ->
// ONE ch8 pass per kk. Window 32x12x12 fp32 = 18.4 KB LDS -> 8 blocks/CU.
// In-loop clamp-aware separable weights (== reference's valid-masked
// bilinear). Global fallback for offsets escaping the +-2 band (never taken).
// ---------------------------------------------------------------------------
__global__ __launch_bounds__(256) void sampler(const float* __restrict__ feature,
                                               const float* __restrict__ pred,
                                               const float* __restrict__ woff,
                                               uint16_t* __restrict__ S) {
    __shared__ float ft[SCH * WIN * WIN];  // 18432 B

    int tid = threadIdx.x;
    int cb = blockIdx.y, b = blockIdx.z;
    int ch0 = cb * SCH;                    // global channel base
    int g = ch0 >> 6;                      // group
    int ty = blockIdx.x / (WW / TS), tx = blockIdx.x % (WW / TS);
    int r0 = ty * TS, c0 = tx * TS;
    int rlo = min(max(r0 - 2, 0), HH - WIN);
    int clo = min(max(c0 - 2, 0), WW - WIN);

    // ---- stage feature window [ch][r][q] (fp32), 4608 elems / 256 thr
    const float* fg = feature + ((size_t)(b * CIN + ch0)) * HW;
    for (int e = tid; e < SCH * WIN * WIN; e += 256) {
        int ch = e / (WIN * WIN);
        int re = e - ch * (WIN * WIN);
        int rr = re / WIN, cc = re - rr * WIN;
        ft[e] = fg[(size_t)ch * HW + (rlo + rr) * WW + clo + cc];
    }
    __syncthreads();

    int lane = tid & 63, wv = tid >> 6;    // wv in {0..3}: channels wv*8..+8
    int lr = lane >> 3, lc = lane & 7;
    int hy = r0 + lr, hx = c0 + lc;
    int p = hy * WW + hx;
    float4 ps4 = *(const float4*)(pred + ((size_t)b * HW + p) * 4);

    const float* ftw = ft + (wv * 8) * (WIN * WIN);
    const float* fgw = fg + (size_t)(wv * 8) * HW;      // fallback base
    int kb_base = cb * 4 + wv;             // (ch0 + wv*8)/8

#pragma unroll
    for (int kk = 0; kk < KK; ++kk) {
        const float* wy = woff + (g * KK + kk) * 8;     // uniform -> s_load
        float offy = ps4.x * wy[0] + ps4.y * wy[1] + ps4.z * wy[2] + ps4.w * wy[3];
        float offx = ps4.x * wy[4] + ps4.y * wy[5] + ps4.z * wy[6] + ps4.w * wy[7];
        float py = (float)(hy - 1 + kk / 3) + offy;
        float px = (float)(hx - 1 + kk % 3) + offx;
        float fy = floorf(py), fx = floorf(px);
        int y0 = (int)fy, x0 = (int)fx;
        float ly = py - fy, lx = px - fx;
        int r = min(max(y0, 0), HH - 2);
        int q = min(max(x0, 0), WW - 2);
        float wyA = (y0 == r) ? (1.f - ly) : ((y0 == -1) ? ly : 0.f);
        float wyB = (y0 == r) ? ly : ((y0 == HH - 1) ? (1.f - ly) : 0.f);
        float wxA = (x0 == q) ? (1.f - lx) : ((x0 == -1) ? lx : 0.f);
        float wxB = (x0 == q) ? lx : ((x0 == WW - 1) ? (1.f - lx) : 0.f);
        float c00 = wyA * wxA, c01 = wyA * wxB;
        float c10 = wyB * wxA, c11 = wyB * wxB;

        bool fast = (r >= rlo) & (r <= rlo + WIN - 2) &
                    (q >= clo) & (q <= clo + WIN - 2);

        uint16_t* Sp = S + (((size_t)b * KB + (kk * 32 + kb_base)) * HW + p) * 8;
        uint32_t pk[4];

        if (fast) {
            int base = (r - rlo) * WIN + (q - clo);
#pragma unroll
            for (int ep = 0; ep < 4; ++ep) {
                const float* f0 = ftw + (2 * ep) * (WIN * WIN) + base;
                const float* f1 = f0 + (WIN * WIN);
                float v0 = c00 * f0[0] + c01 * f0[1] + c10 * f0[WIN] + c11 * f0[WIN + 1];
                float v1 = c00 * f1[0] + c01 * f1[1] + c10 * f1[WIN] + c11 * f1[WIN + 1];
                pk[ep] = pk2bf(v0, v1);
            }
        } else {
            size_t gb = (size_t)r * WW + q;
#pragma unroll
            for (int ep = 0; ep < 4; ++ep) {
                const float* f0 = fgw + (size_t)(2 * ep) * HW + gb;
                const float* f1 = f0 + HW;
                float v0 = c00 * f0[0] + c01 * f0[1] + c10 * f0[WW] + c11 * f0[WW + 1];
                float v1 = c00 * f1[0] + c01 * f1[1] + c10 * f1[WW] + c11 * f1[WW + 1];
                pk[ep] = pk2bf(v0, v1);
            }
        }
        u32x4 vv = {pk[0], pk[1], pk[2], pk[3]};
        *(u32x4*)(Sp) = vv;
    }
}

// ---------------------------------------------------------------------------
// Kernel 3: out[b,o,p] = relu( sum_k A[o,k] * S[k,p] )  (bf16 MFMA 16x16x32)
// 128x64 tile, grid 576. A fragments load GLOBAL->VGPR (L2-hot 1.2 MB panel,
// double-buffered regs, prefetched 1 step ahead) -- A never touches LDS.
// LDS holds only B (2 x 8 KB double buffer). Per wave-step: 4 ds_read_b128
// feed 16 MFMAs -> LDS-pipe ~6 us chip-wide (was ~51: the round-7 bound).
// Counted vmcnt(2): only ops newer than step-t's A-regs are the 2 B-stage
// loads for t+1, which stay in flight across the barrier.
// ---------------------------------------------------------------------------
__global__ __launch_bounds__(256, 3) void gemm_kernel(const uint16_t* __restrict__ S,
                                                      const uint16_t* __restrict__ Ablk,
                                                      float* __restrict__ out) {
    __shared__ uint16_t sB[2][8 * 64 * 8];   // [buf][kb-chunk][px][8], 8 KB/buf

    int tid = threadIdx.x;
    int lane = tid & 63, wv = tid >> 6;
    int wr = wv >> 1, wc = wv & 1;           // wave tile: rows wr*64, cols wc*32
    int col0 = blockIdx.x * 64;              // p tile (144)
    int o0   = blockIdx.y * 128;             // o tile (2)
    int b    = blockIdx.z;

    const uint16_t* Bg = S + (size_t)b * KB * HW * 8;

    f32x4 acc[4][2];
#pragma unroll
    for (int m = 0; m < 4; ++m)
#pragma unroll
        for (int n = 0; n < 2; ++n) acc[m][n] = (f32x4){0.f, 0.f, 0.f, 0.f};

    int kc = lane >> 4, il = lane & 15;
    const int NT = KTOT / 64;                // 36

    // A fragment rows for this wave: o0 + wr*64 + m*16 + il, k-chunk kc+4h
    const uint16_t* Arow = Ablk + ((size_t)(o0 + wr * 64 + il)) * 8;

    auto LOADA = [&](int t, short8 (&af)[2][4]) {
#pragma unroll
        for (int h = 0; h < 2; ++h)
#pragma unroll
            for (int m = 0; m < 4; ++m)
                af[h][m] = *(const short8*)(Arow + ((size_t)(t * 8 + h * 4 + kc) * 256 + m * 16) * 8);
    };

    // wave wv stages B kb-chunks {t*8+wv*2, t*8+wv*2+1} (2 loads/wave)
    auto STAGEB = [&](int t, int buf) {
#pragma unroll
        for (int j = 0; j < 2; ++j) {
            int kb = t * 8 + wv * 2 + j;
            int lc_ = wv * 2 + j;
            __builtin_amdgcn_global_load_lds(
                (const __attribute__((address_space(1))) uint32_t*)
                    (Bg + ((size_t)kb * HW + col0 + lane) * 8),
                (__attribute__((address_space(3))) uint32_t*)
                    (&sB[buf][(lc_ * 64 + lane) * 8]),
                16, 0, 0);
        }
    };

    short8 afA[2][4], afB[2][4];

    // prologue: A(0) then B(0), B(1)  [queue: A0:8, B0:2, B1:2]
    LOADA(0, afA);
    STAGEB(0, 0);
    STAGEB(1, 1);

    auto ITER = [&](int t, short8 (&use)[2][4], short8 (&next)[2][4], int buf) {
        // wait: A(t) + B(t) complete; B(t+1)'s 2 loads stay in flight
        if (t < NT - 1) {
            asm volatile("s_waitcnt vmcnt(2)\n\ts_barrier" ::: "memory");
        } else {
            asm volatile("s_waitcnt vmcnt(0)\n\ts_barrier" ::: "memory");
        }
        __builtin_amdgcn_sched_barrier(0);

        if (t + 1 < NT) LOADA(t + 1, next);  // prefetch A for next step

        short8 bf[2][2];
#pragma unroll
        for (int h = 0; h < 2; ++h)
#pragma unroll
            for (int n = 0; n < 2; ++n)
                bf[h][n] = *(const short8*)(&sB[buf][((h * 4 + kc) * 64 + wc * 32 + n * 16 + il) * 8]);

#pragma unroll
        for (int h = 0; h < 2; ++h)
#pragma unroll
            for (int m = 0; m < 4; ++m)
#pragma unroll
                for (int n = 0; n < 2; ++n)
                    acc[m][n] = __builtin_amdgcn_mfma_f32_16x16x32_bf16(use[h][m], bf[h][n], acc[m][n], 0, 0, 0);

        // all waves done reading sB[buf], then refill it for step t+2
        asm volatile("s_waitcnt lgkmcnt(0)\n\ts_barrier" ::: "memory");
        __builtin_amdgcn_sched_barrier(0);
        if (t + 2 < NT) STAGEB(t + 2, buf);
    };

    for (int tt = 0; tt < NT; tt += 2) {     // NT=36 even; static A-reg rotation
        ITER(tt,     afA, afB, 0);
        ITER(tt + 1, afB, afA, 1);
    }

    int r4 = (lane >> 4) * 4;
    size_t obase = ((size_t)b * COUT + o0 + wr * 64) * HW + col0 + wc * 32;
#pragma unroll
    for (int m = 0; m < 4; ++m)
#pragma unroll
        for (int n = 0; n < 2; ++n)
#pragma unroll
            for (int r = 0; r < 4; ++r) {
                float v = acc[m][n][r];
                v = v > 0.f ? v : 0.f;
                out[obase + (size_t)(m * 16 + r4 + r) * HW + n * 16 + il] = v;
            }
}

// ---------------------------------------------------------------------------
extern "C" void kernel_launch(void* const* d_in, const int* in_sizes, int n_in,
                              void* d_out, int out_size, void* d_ws, size_t ws_size,
                              hipStream_t stream) {
    (void)in_sizes; (void)n_in; (void)out_size; (void)ws_size;
    const float* feature = (const float*)d_in[0];
    const float* pred    = (const float*)d_in[1];
    const float* woff    = (const float*)d_in[2];
    const float* wdef    = (const float*)d_in[3];
    float* out = (float*)d_out;

    const size_t S_BYTES = (size_t)NB * KB * HW * 8 * 2;   // 84,934,656
    uint16_t* S    = (uint16_t*)d_ws;
    uint16_t* Ablk = (uint16_t*)((char*)d_ws + S_BYTES);

    hipLaunchKernelGGL(prep_A, dim3(288), dim3(256), 0, stream, wdef, Ablk);
    hipLaunchKernelGGL(sampler, dim3((HH / TS) * (WW / TS), CIN / SCH, NB), dim3(256), 0, stream,
                       feature, pred, woff, S);
    hipLaunchKernelGGL(gemm_kernel, dim3(HW / 64, COUT / 128, NB), dim3(256), 0, stream,
                       S, Ablk, out);
}

// Round 10
// 77.123 us; speedup vs baseline: 1.2152x; 1.1270x over previous
//
#include <hip/hip_runtime.h>
#include <hip/hip_bf16.h>
#include <stdint.h>

#define HH   96
#define WW   96
#define HW   9216
#define CIN  256
#define COUT 256
#define NB   2      // batch
#define NG   4      // groups
#define CG   64     // channels per group
#define KK   9
#define KTOT 2304   // CIN*KK
#define KB   288    // KTOT/8
#define TS   8      // sampler pixel tile side
#define WIN  12     // staged window side (TS + 4)
#define SCH  32     // sampler channels per block (one 8-ch pass per wave)

typedef __attribute__((ext_vector_type(8))) short short8;
typedef __attribute__((ext_vector_type(4))) float f32x4;
typedef __attribute__((ext_vector_type(4))) uint32_t u32x4;

__device__ __forceinline__ uint32_t pk2bf(float v0, float v1) {
    __hip_bfloat162 h = __float22bfloat162_rn(make_float2(v0, v1));  // v_cvt_pk_bf16_f32
    uint32_t u;
    __builtin_memcpy(&u, &h, 4);
    return u;
}

// ---------------------------------------------------------------------------
// Kernel 1: w_deform (COUT x CIN x 9 fp32) -> bf16, flat blocked [kb][o][8]
// K-order is kk-major: k' = kk*256 + c  (must match sampler's S layout)
// ---------------------------------------------------------------------------
__global__ __launch_bounds__(256) void prep_A(const float* __restrict__ wd,
                                              uint16_t* __restrict__ Ablk) {
    int t  = blockIdx.x * 256 + threadIdx.x;   // 73728 = 256*288
    int kb = t % KB;
    int o  = t / KB;
    int kkA = kb >> 5;            // (kb*8)/256
    int c0A = (kb & 31) * 8;      // (kb*8)%256
    const float* src = wd + (size_t)o * KTOT + c0A * KK + kkA;
    float a[8];
#pragma unroll
    for (int e = 0; e < 8; ++e) a[e] = src[e * KK];
    uint16_t* dst = Ablk + ((size_t)kb * 256 + o) * 8;
    u32x4 v;
    v.x = pk2bf(a[0], a[1]);
    v.y = pk2bf(a[2], a[3]);
    v.z = pk2bf(a[4], a[5]);
    v.w = pk2bf(a[6], a[7]);
    *(u32x4*)dst = v;
}

// ---------------------------------------------------------------------------
// Kernel 2: offsets + bilinear sampling -> S[b][kb][p][8] bf16 (kk-major K)
// block = 8x8 pixel tile x 32 channels, 256 thr; wave wv owns 8 channels ->
// ONE ch8 pass per kk. Window 32x12x12 fp32 = 18.4 KB LDS -> 8 blocks/CU.
// In-loop clamp-aware separable weights (== reference's valid-masked
// bilinear). Global fallback for offsets escaping the +-2 band (never taken).
// ---------------------------------------------------------------------------
__global__ __launch_bounds__(256) void sampler(const float* __restrict__ feature,
                                               const float* __restrict__ pred,
                                               const float* __restrict__ woff,
                                               uint16_t* __restrict__ S) {
    __shared__ float ft[SCH * WIN * WIN];  // 18432 B

    int tid = threadIdx.x;
    int cb = blockIdx.y, b = blockIdx.z;
    int ch0 = cb * SCH;                    // global channel base
    int g = ch0 >> 6;                      // group
    int ty = blockIdx.x / (WW / TS), tx = blockIdx.x % (WW / TS);
    int r0 = ty * TS, c0 = tx * TS;
    int rlo = min(max(r0 - 2, 0), HH - WIN);
    int clo = min(max(c0 - 2, 0), WW - WIN);

    // ---- stage feature window [ch][r][q] (fp32), 4608 elems / 256 thr
    const float* fg = feature + ((size_t)(b * CIN + ch0)) * HW;
    for (int e = tid; e < SCH * WIN * WIN; e += 256) {
        int ch = e / (WIN * WIN);
        int re = e - ch * (WIN * WIN);
        int rr = re / WIN, cc = re - rr * WIN;
        ft[e] = fg[(size_t)ch * HW + (rlo + rr) * WW + clo + cc];
    }
    __syncthreads();

    int lane = tid & 63, wv = tid >> 6;    // wv in {0..3}: channels wv*8..+8
    int lr = lane >> 3, lc = lane & 7;
    int hy = r0 + lr, hx = c0 + lc;
    int p = hy * WW + hx;
    float4 ps4 = *(const float4*)(pred + ((size_t)b * HW + p) * 4);

    const float* ftw = ft + (wv * 8) * (WIN * WIN);
    const float* fgw = fg + (size_t)(wv * 8) * HW;      // fallback base
    int kb_base = cb * 4 + wv;             // (ch0 + wv*8)/8

#pragma unroll
    for (int kk = 0; kk < KK; ++kk) {
        const float* wy = woff + (g * KK + kk) * 8;     // uniform -> s_load
        float offy = ps4.x * wy[0] + ps4.y * wy[1] + ps4.z * wy[2] + ps4.w * wy[3];
        float offx = ps4.x * wy[4] + ps4.y * wy[5] + ps4.z * wy[6] + ps4.w * wy[7];
        float py = (float)(hy - 1 + kk / 3) + offy;
        float px = (float)(hx - 1 + kk % 3) + offx;
        float fy = floorf(py), fx = floorf(px);
        int y0 = (int)fy, x0 = (int)fx;
        float ly = py - fy, lx = px - fx;
        int r = min(max(y0, 0), HH - 2);
        int q = min(max(x0, 0), WW - 2);
        float wyA = (y0 == r) ? (1.f - ly) : ((y0 == -1) ? ly : 0.f);
        float wyB = (y0 == r) ? ly : ((y0 == HH - 1) ? (1.f - ly) : 0.f);
        float wxA = (x0 == q) ? (1.f - lx) : ((x0 == -1) ? lx : 0.f);
        float wxB = (x0 == q) ? lx : ((x0 == WW - 1) ? (1.f - lx) : 0.f);
        float c00 = wyA * wxA, c01 = wyA * wxB;
        float c10 = wyB * wxA, c11 = wyB * wxB;

        bool fast = (r >= rlo) & (r <= rlo + WIN - 2) &
                    (q >= clo) & (q <= clo + WIN - 2);

        uint16_t* Sp = S + (((size_t)b * KB + (kk * 32 + kb_base)) * HW + p) * 8;
        uint32_t pk[4];

        if (fast) {
            int base = (r - rlo) * WIN + (q - clo);
#pragma unroll
            for (int ep = 0; ep < 4; ++ep) {
                const float* f0 = ftw + (2 * ep) * (WIN * WIN) + base;
                const float* f1 = f0 + (WIN * WIN);
                float v0 = c00 * f0[0] + c01 * f0[1] + c10 * f0[WIN] + c11 * f0[WIN + 1];
                float v1 = c00 * f1[0] + c01 * f1[1] + c10 * f1[WIN] + c11 * f1[WIN + 1];
                pk[ep] = pk2bf(v0, v1);
            }
        } else {
            size_t gb = (size_t)r * WW + q;
#pragma unroll
            for (int ep = 0; ep < 4; ++ep) {
                const float* f0 = fgw + (size_t)(2 * ep) * HW + gb;
                const float* f1 = f0 + HW;
                float v0 = c00 * f0[0] + c01 * f0[1] + c10 * f0[WW] + c11 * f0[WW + 1];
                float v1 = c00 * f1[0] + c01 * f1[1] + c10 * f1[WW] + c11 * f1[WW + 1];
                pk[ep] = pk2bf(v0, v1);
            }
        }
        u32x4 vv = {pk[0], pk[1], pk[2], pk[3]};
        *(u32x4*)(Sp) = vv;
    }
}

// ---------------------------------------------------------------------------
// Kernel 3: independent-wave GEMM. out[b,o,p] = relu(sum_k A[o,k]*S[k,p]).
// One 64-thread block (1 wave) owns a 64x64 tile: acc 4x4, A/B fragments
// global->VGPR (256B coalesced segments, L2-served), 2-step register
// pipeline, STATIC rotation, consume-BEFORE-reload (fixes round-9 bug).
// NO LDS, NO barriers, NO inline asm. XCD-chunked swizzle: the 4 my-blocks
// sharing one (b,p-slice) of S run consecutively on the SAME XCD -> 3/4 of
// S re-reads are L2 hits; A panel (1.2 MB) L2-resident.
// ---------------------------------------------------------------------------
__global__ __launch_bounds__(64, 2) void gemm_kernel(const uint16_t* __restrict__ S,
                                                     const uint16_t* __restrict__ Ablk,
                                                     float* __restrict__ out) {
    int lane = threadIdx.x;
    // swizzle: bid -> xcd (bid&7), j = bid>>3; my fastest within an XCD chunk
    int bid = blockIdx.x;                  // 0..1151
    int xcd = bid & 7;
    int j   = bid >> 3;                    // 0..143
    int my  = j & 3;
    int pairid = xcd * 36 + (j >> 2);      // 0..287 = b*144 + py
    int b  = pairid / 144;
    int py = pairid % 144;
    int o0 = my * 64, col0 = py * 64;
    int kc = lane >> 4, il = lane & 15;

    // per-lane bases; k-chunk kb = t*4 + kc at step t (72 steps of K=32)
    const uint16_t* Ap = Ablk + ((size_t)kc * 256 + o0 + il) * 8;
    const uint16_t* Bp = S + (size_t)b * KB * HW * 8 + ((size_t)kc * HW + col0 + il) * 8;
    const size_t Astep = (size_t)4 * 256 * 8;   // elems per K32 step
    const size_t Bstep = (size_t)4 * HW * 8;

    f32x4 acc[4][4];
#pragma unroll
    for (int m = 0; m < 4; ++m)
#pragma unroll
        for (int n = 0; n < 4; ++n) acc[m][n] = (f32x4){0.f, 0.f, 0.f, 0.f};

    const int NT = KTOT / 32;              // 72 (even)

    short8 a0[4], b0[4], a1[4], b1[4];

#define LOADT(t, areg, breg)                                                   \
    {                                                                          \
        const uint16_t* ap = Ap + (size_t)(t) * Astep;                         \
        const uint16_t* bp = Bp + (size_t)(t) * Bstep;                         \
        areg[0] = *(const short8*)(ap + 0 * 16 * 8);                           \
        areg[1] = *(const short8*)(ap + 1 * 16 * 8);                           \
        areg[2] = *(const short8*)(ap + 2 * 16 * 8);                           \
        areg[3] = *(const short8*)(ap + 3 * 16 * 8);                           \
        breg[0] = *(const short8*)(bp + 0 * 16 * 8);                           \
        breg[1] = *(const short8*)(bp + 1 * 16 * 8);                           \
        breg[2] = *(const short8*)(bp + 2 * 16 * 8);                           \
        breg[3] = *(const short8*)(bp + 3 * 16 * 8);                           \
    }

#define MFMAT(areg, breg)                                                      \
    {                                                                          \
        _Pragma("unroll")                                                      \
        for (int m = 0; m < 4; ++m)                                            \
            _Pragma("unroll")                                                  \
            for (int n = 0; n < 4; ++n)                                        \
                acc[m][n] = __builtin_amdgcn_mfma_f32_16x16x32_bf16(           \
                    areg[m], breg[n], acc[m][n], 0, 0, 0);                     \
    }

    LOADT(0, a0, b0);
    LOADT(1, a1, b1);

    for (int tt = 0; tt < NT; tt += 2) {
        MFMAT(a0, b0);                            // consume step tt
        if (tt + 2 < NT) LOADT(tt + 2, a0, b0);   // then refill for tt+2
        MFMAT(a1, b1);                            // consume step tt+1
        if (tt + 3 < NT) LOADT(tt + 3, a1, b1);   // then refill for tt+3
    }
#undef LOADT
#undef MFMAT

    // C/D layout: col = lane&15 (p), row = (lane>>4)*4 + r (o); fused ReLU
    int r4 = kc * 4;
    size_t obase = ((size_t)b * COUT + o0) * HW + col0;
#pragma unroll
    for (int m = 0; m < 4; ++m)
#pragma unroll
        for (int n = 0; n < 4; ++n)
#pragma unroll
            for (int r = 0; r < 4; ++r) {
                float v = acc[m][n][r];
                v = v > 0.f ? v : 0.f;
                out[obase + (size_t)(m * 16 + r4 + r) * HW + n * 16 + il] = v;
            }
}

// ---------------------------------------------------------------------------
extern "C" void kernel_launch(void* const* d_in, const int* in_sizes, int n_in,
                              void* d_out, int out_size, void* d_ws, size_t ws_size,
                              hipStream_t stream) {
    (void)in_sizes; (void)n_in; (void)out_size; (void)ws_size;
    const float* feature = (const float*)d_in[0];
    const float* pred    = (const float*)d_in[1];
    const float* woff    = (const float*)d_in[2];
    const float* wdef    = (const float*)d_in[3];
    float* out = (float*)d_out;

    const size_t S_BYTES = (size_t)NB * KB * HW * 8 * 2;   // 84,934,656
    uint16_t* S    = (uint16_t*)d_ws;
    uint16_t* Ablk = (uint16_t*)((char*)d_ws + S_BYTES);

    hipLaunchKernelGGL(prep_A, dim3(288), dim3(256), 0, stream, wdef, Ablk);
    hipLaunchKernelGGL(sampler, dim3((HH / TS) * (WW / TS), CIN / SCH, NB), dim3(256), 0, stream,
                       feature, pred, woff, S);
    hipLaunchKernelGGL(gemm_kernel, dim3(8 * (HW / 64) * NB / 8 * 4), dim3(64), 0, stream,
                       S, Ablk, out);
}